// Round 7
// baseline (1657.723 us; speedup 1.0000x reference)
//
#include <hip/hip_runtime.h>
#include <hip/hip_bf16.h>
#include <math.h>

#define PIX 2304
#define CCH 256
#define CP  589824      // CCH*PIX
#define NCP 1769472     // 3*CP
#define KC  4608        // conv K = 512*9
#define PADR 2512       // padded rows per image

typedef __hip_bfloat16 bf16;
typedef __attribute__((ext_vector_type(8))) short bf16x8;
typedef __attribute__((ext_vector_type(4))) float f32x4;

__device__ __forceinline__ float sigmoidf_(float x){ return 1.f/(1.f+__expf(-x)); }

__device__ __forceinline__ void gl_lds16(const bf16* g, bf16* lds){
    __builtin_amdgcn_global_load_lds(
        (const __attribute__((address_space(1))) void*)g,
        (__attribute__((address_space(3))) void*)lds, 16, 0, 0);
}
#define FENCE() asm volatile("" ::: "memory")

// =======================================================================
// Fused flash attention over 9 (i,j) pairs. Q = t_i (ti_i on diagonal),
// K = hp_j (P x C). V^T = hcp_j (C x P) read DIRECT from global (L1/L2).
// 512 thr (8 waves), QBLK=128, KVBLK=64. K dbuf LDS, counted-vmcnt pipeline.
// LDS = 64KB (Ks) + 16KB (Ps) = 80KB -> 2 blocks/CU.
// =======================================================================
__global__ __launch_bounds__(512) void fattn_k(
    const bf16* __restrict__ T, const bf16* __restrict__ Ti,
    const bf16* __restrict__ Khp, const bf16* __restrict__ Vcp,
    bf16* __restrict__ Ob)
{
    __shared__ bf16 Ks[2][64*256];   // [q][d], chunk-swizzled (32 chunks/row)
    __shared__ bf16 Ps[8][16*64];    // per-wave P, chunk-major
    const int z = blockIdx.z, i = z/3, j = z%3;
    const bf16* Q  = ((i==j)? Ti : T) + (long)i*CP;
    const bf16* Kp = Khp + (long)j*CP;
    const bf16* Vp = Vcp + (long)j*CP;
    const int tid = threadIdx.x, l = tid & 63, w = tid >> 6;
    const int q0 = blockIdx.x*128;

    bf16x8 qf[8];
    {
        const bf16* qr = Q + (long)(q0 + w*16 + (l&15))*256 + (l>>4)*8;
        #pragma unroll
        for (int ks=0; ks<8; ++ks) qf[ks] = *(const bf16x8*)(qr + ks*32);
    }
    f32x4 oacc[16];
    #pragma unroll
    for (int nf=0; nf<16; ++nf) oacc[nf] = (f32x4){0.f,0.f,0.f,0.f};
    float mrun[4] = {-3e38f,-3e38f,-3e38f,-3e38f};
    float lrun[4] = {0.f,0.f,0.f,0.f};

    auto stageK = [&](int buf, int t){
        const int kq = t*64;
        #pragma unroll
        for (int u=0; u<4; ++u){
            int idx = u*512 + tid;
            int rr = idx>>5, cc = idx&31;
            gl_lds16(Kp + (long)(kq+rr)*256 + ((cc ^ (rr&7))<<3),
                     &Ks[buf][(u*512 + (tid & ~63))*8]);
        }
    };

    stageK(0, 0);
    int cur = 0;
    for (int t=0; t<36; ++t){
        if (t+1 < 36){
            stageK(cur^1, t+1);
            asm volatile("s_waitcnt vmcnt(4)" ::: "memory");
        } else {
            asm volatile("s_waitcnt vmcnt(0)" ::: "memory");
        }
        __builtin_amdgcn_s_barrier();
        FENCE();

        // ---- QK^T: S[16 rows][64 q] per wave ----
        f32x4 sacc[4];
        #pragma unroll
        for (int nf=0; nf<4; ++nf) sacc[nf] = (f32x4){0.f,0.f,0.f,0.f};
        __builtin_amdgcn_s_setprio(1);
        #pragma unroll
        for (int ks=0; ks<8; ++ks){
            #pragma unroll
            for (int nf=0; nf<4; ++nf){
                int row = nf*16 + (l&15);
                int phys = (ks*4 + (l>>4)) ^ (row&7);
                bf16x8 b = *(const bf16x8*)&Ks[cur][row*256 + phys*8];
                sacc[nf] = __builtin_amdgcn_mfma_f32_16x16x32_bf16(qf[ks], b, sacc[nf], 0,0,0);
            }
        }
        __builtin_amdgcn_s_setprio(0);
        FENCE();
        __builtin_amdgcn_s_barrier();   // Ks[cur] consumed -> may be restaged next iter
        FENCE();

        // ---- online softmax ----
        float alpha[4];
        #pragma unroll
        for (int r=0; r<4; ++r){
            float v = fmaxf(fmaxf(sacc[0][r], sacc[1][r]), fmaxf(sacc[2][r], sacc[3][r]));
            v = fmaxf(v, __shfl_xor(v,1)); v = fmaxf(v, __shfl_xor(v,2));
            v = fmaxf(v, __shfl_xor(v,4)); v = fmaxf(v, __shfl_xor(v,8));
            float mn = fmaxf(mrun[r], v);
            alpha[r] = __expf(mrun[r] - mn);
            mrun[r] = mn;
            float rs = 0.f;
            #pragma unroll
            for (int nf=0; nf<4; ++nf){
                float p = __expf(sacc[nf][r] - mn);
                sacc[nf][r] = p; rs += p;
            }
            rs += __shfl_xor(rs,1); rs += __shfl_xor(rs,2);
            rs += __shfl_xor(rs,4); rs += __shfl_xor(rs,8);
            lrun[r] = lrun[r]*alpha[r] + rs;
        }
        // ---- P -> LDS (per-wave, chunk-major) ----
        #pragma unroll
        for (int nf=0; nf<4; ++nf)
            #pragma unroll
            for (int r=0; r<4; ++r){
                int row = (l>>4)*4 + r;
                int col = nf*16 + (l&15);
                Ps[w][(col>>3)*128 + row*8 + (col&7)] = __float2bfloat16(sacc[nf][r]);
            }
        FENCE();
        // ---- rescale O ----
        #pragma unroll
        for (int nf=0; nf<16; ++nf)
            #pragma unroll
            for (int r=0; r<4; ++r) oacc[nf][r] *= alpha[r];
        // ---- PV: O += P * V, V^T frags straight from global ----
        const bf16* vb = Vp + t*64 + (l>>4)*8;
        __builtin_amdgcn_s_setprio(1);
        #pragma unroll
        for (int ks2=0; ks2<2; ++ks2){
            bf16x8 pa = *(const bf16x8*)&Ps[w][(ks2*4 + (l>>4))*128 + (l&15)*8];
            #pragma unroll
            for (int nf=0; nf<16; ++nf){
                bf16x8 bv = *(const bf16x8*)(vb + (long)(nf*16 + (l&15))*2304 + ks2*32);
                oacc[nf] = __builtin_amdgcn_mfma_f32_16x16x32_bf16(pa, bv, oacc[nf], 0,0,0);
            }
        }
        __builtin_amdgcn_s_setprio(0);
        cur ^= 1;
    }

    #pragma unroll
    for (int r=0; r<4; ++r) lrun[r] = 1.f / lrun[r];
    bf16* ob = Ob + (long)z*CP;
    const int prow0 = q0 + w*16 + (l>>4)*4;
    #pragma unroll
    for (int nf=0; nf<16; ++nf){
        int c = nf*16 + (l&15);
        #pragma unroll
        for (int r=0; r<4; ++r)
            ob[(long)(prow0+r)*256 + c] = __float2bfloat16(oacc[nf][r]*lrun[r]);
    }
}

// =======================================================================
// Unified bf16 MFMA GEMM, BT layout, XOR-swizzled LDS, counted-vmcnt dbuf.
// EPI 0: bf16 out.  EPI 2: fp32 sigmoid(acc+bias0[m]) * aux[n*auxld+m].
// =======================================================================
template<int EPI, int BN>
__global__ __launch_bounds__(256) void mgemm_k(
    const bf16* __restrict__ A0, const bf16* __restrict__ A1, int diagz,
    const bf16* __restrict__ B,
    float* __restrict__ o0, bf16* __restrict__ ob,
    const bf16* __restrict__ aux, const float* __restrict__ bias0,
    int M, int N, int lda, int ldb, int ldc, int auxld,
    long bsA, long bsB, long bsC, long bsAux,
    int nzJ, int Ksub, long bsKc)
{
    __shared__ bf16 As[2][128*64];
    __shared__ bf16 Bs[2][BN*64];
    const int z = blockIdx.z;
    const int jz = z % nzJ, kc = z / nzJ;
    const bf16* Ap = ((jz==diagz)?A1:A0) + jz*bsA + (long)blockIdx.x*128*lda;
    const bf16* Bp = B + jz*bsB + (long)blockIdx.y*BN*ldb;
    const int tid = threadIdx.x, l = tid & 63;
    const int wvu = tid & ~63;
    const int wr = tid>>7, wc = (tid>>6)&1;
    constexpr int NF = BN/32;
    f32x4 acc[4][NF];
    #pragma unroll
    for (int i=0;i<4;++i)
        #pragma unroll
        for (int j=0;j<NF;++j) acc[i][j] = (f32x4){0.f,0.f,0.f,0.f};

    auto stage = [&](int buf, int kb){
        #pragma unroll
        for (int u=0;u<4;++u){
            int idx = u*256 + tid;
            int row = idx>>3, g = (idx&7) ^ (row&7);
            gl_lds16(Ap + (long)row*lda + kb + g*8, &As[buf][(u*256+wvu)*8]);
        }
        #pragma unroll
        for (int u=0;u<BN/32;++u){
            int idx = u*256 + tid;
            int row = idx>>3, g = (idx&7) ^ (row&7);
            gl_lds16(Bp + (long)row*ldb + kb + g*8, &Bs[buf][(u*256+wvu)*8]);
        }
    };

    const int kbeg = kc*Ksub;
    const int nk = Ksub >> 6;
    stage(0, kbeg);
    int cur = 0;
    for (int t=0; t<nk; ++t){
        if (t+1 < nk){
            stage(cur^1, kbeg + (t+1)*64);
            if constexpr (BN==64) asm volatile("s_waitcnt vmcnt(6)" ::: "memory");
            else                  asm volatile("s_waitcnt vmcnt(8)" ::: "memory");
        } else {
            asm volatile("s_waitcnt vmcnt(0)" ::: "memory");
        }
        __builtin_amdgcn_s_barrier();
        FENCE();
        #pragma unroll
        for (int ks=0; ks<64; ks+=32){
            bf16x8 af[4], bfr[NF];
            #pragma unroll
            for (int i=0;i<4;++i){
                int row = wr*64 + i*16 + (l&15);
                af[i] = *(const bf16x8*)&As[cur][row*64 + ((((ks>>3)+(l>>4)) ^ (row&7))<<3)];
            }
            #pragma unroll
            for (int j=0;j<NF;++j){
                int row = wc*(BN/2) + j*16 + (l&15);
                bfr[j] = *(const bf16x8*)&Bs[cur][row*64 + ((((ks>>3)+(l>>4)) ^ (row&7))<<3)];
            }
            #pragma unroll
            for (int i=0;i<4;++i)
                #pragma unroll
                for (int j=0;j<NF;++j)
                    acc[i][j] = __builtin_amdgcn_mfma_f32_16x16x32_bf16(af[i], bfr[j], acc[i][j], 0,0,0);
        }
        FENCE();
        __builtin_amdgcn_s_barrier();
        FENCE();
        cur ^= 1;
    }

    const int mb = blockIdx.x*128 + wr*64, nb = blockIdx.y*BN + wc*(BN/2);
    #pragma unroll
    for (int i=0;i<4;++i)
        #pragma unroll
        for (int j=0;j<NF;++j){
            int gm0 = mb + i*16 + ((l>>4)<<2);
            int gn  = nb + j*16 + (l&15);
            #pragma unroll
            for (int r=0;r<4;++r){
                int gm = gm0 + r;
                float vacc = acc[i][j][r];
                if (EPI==0){
                    ob[jz*bsC + (long)gm*ldc + gn] = __float2bfloat16(vacc);
                } else {
                    float g = sigmoidf_(vacc + bias0[gm]);
                    float mv = __bfloat162float(aux[jz*bsAux + (long)gn*auxld + gm]);
                    o0[jz*bsC + (long)gm*ldc + gn] = g*mv;
                }
            }
        }
}

// =======================================================================
// Implicit-GEMM 3x3 conv, counted-vmcnt dbuf pipeline.
// =======================================================================
__global__ __launch_bounds__(256) void cgemm2_k(
    const bf16* __restrict__ inpad, const bf16* __restrict__ W,
    float* __restrict__ part, int N)
{
    __shared__ bf16 As[2][128*64];
    __shared__ bf16 Bs[2][64*64];
    const int tid = threadIdx.x, l = tid & 63, wvu = tid & ~63;
    const int wr = tid>>7, wc = (tid>>6)&1;
    const int bx = blockIdx.x, by = blockIdx.y, kc = blockIdx.z;
    const int img = bx/18, m0 = (bx - img*18)*128;
    const bf16* Ab = inpad + (long)img*PADR*512;
    const bf16* Bb = W + (long)by*64*KC;
    f32x4 acc[4][2];
    #pragma unroll
    for (int i=0;i<4;++i){ acc[i][0]=(f32x4){0,0,0,0}; acc[i][1]=(f32x4){0,0,0,0}; }

    auto stageA = [&](int buf, int k0){
        int tap = k0 >> 9, ci0 = k0 & 511;
        int dy = tap/3, dx = tap - 3*dy;
        int shift = (dy-1)*50 + (dx-1);
        #pragma unroll
        for (int u=0;u<4;++u){
            int idx = u*256 + tid;
            int row = idx>>3;
            int om = m0 + row;
            int prow = om + 2*(om/48) + 51 + shift;
            int g = (idx&7) ^ (row&7);
            gl_lds16(Ab + (long)prow*512 + ci0 + g*8, &As[buf][(u*256+wvu)*8]);
        }
    };
    auto stageB = [&](int buf, int k0){
        #pragma unroll
        for (int u=0;u<2;++u){
            int idx = u*256 + tid;
            int row = idx>>3;
            int g = (idx&7) ^ (row&7);
            gl_lds16(Bb + (long)row*KC + k0 + g*8, &Bs[buf][(u*256+wvu)*8]);
        }
    };

    const int kbeg = kc*2304;
    stageA(0, kbeg); stageB(0, kbeg);
    int cur = 0;
    for (int t=0; t<36; ++t){
        if (t+1 < 36){
            stageA(cur^1, kbeg+(t+1)*64); stageB(cur^1, kbeg+(t+1)*64);
            asm volatile("s_waitcnt vmcnt(6)" ::: "memory");
        } else {
            asm volatile("s_waitcnt vmcnt(0)" ::: "memory");
        }
        __builtin_amdgcn_s_barrier();
        FENCE();
        #pragma unroll
        for (int ks=0; ks<64; ks+=32){
            bf16x8 af[4], bfr[2];
            #pragma unroll
            for (int i=0;i<4;++i){
                int row = wr*64 + i*16 + (l&15);
                af[i] = *(const bf16x8*)&As[cur][row*64 + ((((ks>>3)+(l>>4)) ^ (row&7))<<3)];
            }
            #pragma unroll
            for (int j=0;j<2;++j){
                int row = wc*32 + j*16 + (l&15);
                bfr[j] = *(const bf16x8*)&Bs[cur][row*64 + ((((ks>>3)+(l>>4)) ^ (row&7))<<3)];
            }
            #pragma unroll
            for (int i=0;i<4;++i)
                #pragma unroll
                for (int j=0;j<2;++j)
                    acc[i][j] = __builtin_amdgcn_mfma_f32_16x16x32_bf16(af[i], bfr[j], acc[i][j], 0,0,0);
        }
        FENCE();
        __builtin_amdgcn_s_barrier();
        FENCE();
        cur ^= 1;
    }

    float* pbase = part + (long)kc*N*6912 + (long)img*2304;
    #pragma unroll
    for (int i=0;i<4;++i)
        #pragma unroll
        for (int j=0;j<2;++j){
            int gm0 = m0 + wr*64 + i*16 + ((l>>4)<<2);
            int gn  = by*64 + wc*32 + j*16 + (l&15);
            *(f32x4*)&pbase[(long)gn*6912 + gm0] = acc[i][j];
        }
}

// ---- split-K reduce + bias + activation; DUAL r-branch fuses *h (rh) ----
template<int ACT, int DUAL>
__global__ __launch_bounds__(256) void cred_k(const float* __restrict__ part,
        const float* __restrict__ b0, const float* __restrict__ b1,
        float* __restrict__ o0, float* __restrict__ o1,
        const float* __restrict__ hmul, int N)
{
    int id = blockIdx.x*256 + threadIdx.x;
    int c = id / 6912, g = id - c*6912;
    int img = g / 2304, p = g - img*2304;
    float v = part[id] + part[id + (long)N*6912];
    if (DUAL && c >= 256){
        int co = c - 256;
        long oidx = (long)img*CP + (long)co*PIX + p;
        o1[oidx] = sigmoidf_(v + b1[co]) * hmul[oidx];
    } else {
        float r = v + b0[c];
        if (ACT==1) r = sigmoidf_(r);
        else if (ACT==2) r = tanhf(r);
        else r = fmaxf(r, 0.f);
        o0[(long)img*CP + (long)c*PIX + p] = r;
    }
}

__global__ __launch_bounds__(256) void padtr_k(const float* __restrict__ src,
        bf16* __restrict__ dst, int cofs)
{
    __shared__ float tile[64][65];
    const int img = blockIdx.z, p0 = blockIdx.x*64, c0 = blockIdx.y*64;
    const int t = threadIdx.x, tx = t&63, tq = t>>6;
    const float* s = src + (long)img*CP;
    #pragma unroll
    for (int u=0;u<16;++u){
        int r = tq + u*4;
        tile[r][tx] = s[(long)(c0+r)*PIX + p0 + tx];
    }
    __syncthreads();
    bf16* d = dst + (long)img*PADR*512 + cofs + c0;
    #pragma unroll
    for (int u=0;u<16;++u){
        int pl = tq + u*4;
        int p = p0 + pl;
        int prow = p + 2*(p/48) + 51;
        d[(long)prow*512 + tx] = __float2bfloat16(tile[tx][pl]);
    }
}

__global__ __launch_bounds__(256) void convw_k(const float* __restrict__ src,
        bf16* __restrict__ dst, int total)
{
    int idx = blockIdx.x*256 + threadIdx.x;
    if (idx >= total) return;
    int co = idx / KC, r = idx - co*KC;
    int tap = r >> 9, ci = r & 511;
    dst[idx] = __float2bfloat16(src[(long)co*KC + ci*9 + tap]);
}

__global__ __launch_bounds__(256) void prep_h_k(const float* __restrict__ h,
        bf16* __restrict__ hcp, bf16* __restrict__ hp)
{
    __shared__ float tile[64][65];
    const int i = blockIdx.z, p0 = blockIdx.x*64, c0 = blockIdx.y*64;
    const int t = threadIdx.x, tx = t&63, tq = t>>6;
    const float* src = h + (long)i*CP;
    #pragma unroll
    for (int s=0;s<16;++s){
        int r = tq + s*4;
        float v = src[(long)(c0+r)*PIX + p0 + tx];
        tile[r][tx] = v;
        hcp[(long)i*CP + (long)(c0+r)*PIX + p0 + tx] = __float2bfloat16(v);
    }
    __syncthreads();
    #pragma unroll
    for (int s=0;s<16;++s){
        int r = tq + s*4;
        hp[(long)i*CP + (long)(p0+r)*256 + c0 + tx] = __float2bfloat16(tile[tx][r]);
    }
}

__global__ __launch_bounds__(256) void convert_w_k(const float* __restrict__ wint,
    const float* __restrict__ wintra, const float* __restrict__ gw, bf16* __restrict__ o)
{
    int t = blockIdx.x*256 + threadIdx.x;
    int d = t >> 8, c = t & 255;
    o[t]          = __float2bfloat16(wint[c*256 + d]);
    o[65536 + t]  = __float2bfloat16(wintra[c*256 + d]);
    o[131072 + t] = __float2bfloat16(gw[t]);
}

__global__ __launch_bounds__(256) void gatesum_k(const float* __restrict__ g, float* __restrict__ out)
{
    int x = blockIdx.x*256 + threadIdx.x;
    int i = blockIdx.y;
    const float* gi = g + (long)i*3*CP;
    float4 a = ((const float4*)gi)[x];
    float4 b = ((const float4*)gi)[x + CP/4];
    float4 c = ((const float4*)gi)[x + CP/2];
    float4 r; r.x=a.x+b.x+c.x; r.y=a.y+b.y+c.y; r.z=a.z+b.z+c.z; r.w=a.w+b.w+c.w;
    ((float4*)(out + (long)i*CP))[x] = r;
}

__global__ __launch_bounds__(256) void backbone_k(
    const float* __restrict__ frames, const float* __restrict__ W,
    const float* __restrict__ bias, float* __restrict__ v, float* __restrict__ h)
{
    __shared__ float wl[3*64*4];
    const int n = blockIdx.z, o0 = blockIdx.y * 4;
    const int p = blockIdx.x * 256 + threadIdx.x;
    const int y = p / 48, x = p % 48;
    for (int e = threadIdx.x; e < 768; e += 256) {
        int o_sel = e / 192, rem = e % 192, ci = rem / 64, k = rem % 64;
        wl[(ci*64 + k)*4 + o_sel] = W[((long)(o0 + o_sel)*3 + ci)*64 + k];
    }
    __syncthreads();
    float acc[4] = {0.f,0.f,0.f,0.f};
    for (int ci = 0; ci < 3; ++ci) {
        const float* src = frames + (((long)n*3 + ci)*384) * 384;
        #pragma unroll
        for (int k = 0; k < 64; ++k) {
            int ky = k >> 3, kx = k & 7;
            float iv = src[(8*y + ky)*384 + 8*x + kx];
            float4 w = ((const float4*)wl)[ci*64 + k];
            acc[0] += iv*w.x; acc[1] += iv*w.y; acc[2] += iv*w.z; acc[3] += iv*w.w;
        }
    }
    #pragma unroll
    for (int oo = 0; oo < 4; ++oo) {
        float r = fmaxf(acc[oo] + bias[o0 + oo], 0.f);
        long idx = ((long)n*CCH + o0 + oo)*PIX + p;
        v[idx] = r; h[idx] = r;
    }
}

__global__ __launch_bounds__(256) void hupd_k(const float* __restrict__ zg, const float* __restrict__ hc,
                                              float* __restrict__ h)
{
    int idx = blockIdx.x*256 + threadIdx.x;
    float z = zg[idx];
    h[idx] = (1.f - z)*h[idx] + z*hc[idx];
}

__global__ __launch_bounds__(256) void maskpart_k(const float* __restrict__ yin,
        const float* __restrict__ W, float* __restrict__ part)
{
    __shared__ float wl[288];
    const int cb = blockIdx.y * 32;
    for (int e = threadIdx.x; e < 288; e += 256) wl[e] = W[cb*9 + e];
    __syncthreads();
    int id = blockIdx.x*256 + threadIdx.x;
    int n = id / PIX, p = id - n*PIX;
    int y = p / 48, x = p % 48;
    float acc = 0.f;
    for (int ci = 0; ci < 32; ++ci) {
        const float* src = yin + ((long)n*CCH + cb + ci)*PIX;
        #pragma unroll
        for (int dy = 0; dy < 3; ++dy) {
            int yy = y + dy - 1;
            #pragma unroll
            for (int dx = 0; dx < 3; ++dx) {
                int xx = x + dx - 1;
                float iv = (yy >= 0 && yy < 48 && xx >= 0 && xx < 48) ? src[yy*48 + xx] : 0.f;
                acc += iv * wl[ci*9 + dy*3 + dx];
            }
        }
    }
    part[(long)blockIdx.y*(3*PIX) + id] = acc;
}

__global__ __launch_bounds__(256) void maskred_k(const float* __restrict__ part,
        const float* __restrict__ bias, float* __restrict__ out)
{
    int id = blockIdx.x*256 + threadIdx.x;
    float acc = bias[0];
    #pragma unroll
    for (int s = 0; s < 8; ++s) acc += part[(long)s*(3*PIX) + id];
    out[id] = acc;
}

extern "C" void kernel_launch(void* const* d_in, const int* in_sizes, int n_in,
                              void* d_out, int out_size, void* d_ws, size_t ws_size,
                              hipStream_t stream)
{
    const float* frames     = (const float*)d_in[0];
    const float* backbone_w = (const float*)d_in[1];
    const float* backbone_b = (const float*)d_in[2];
    const float* W_intra    = (const float*)d_in[3];
    const float* W_inter    = (const float*)d_in[4];
    const float* gate_w     = (const float*)d_in[5];
    const float* gate_b     = (const float*)d_in[6];
    const float* Wz         = (const float*)d_in[7];
    const float* bz         = (const float*)d_in[8];
    const float* Wr         = (const float*)d_in[9];
    const float* br         = (const float*)d_in[10];
    const float* Wh         = (const float*)d_in[11];
    const float* bh         = (const float*)d_in[12];
    const float* ro_w1      = (const float*)d_in[13];
    const float* ro_b1      = (const float*)d_in[14];
    const float* ro_w2      = (const float*)d_in[15];
    const float* ro_b2      = (const float*)d_in[16];
    float* out = (float*)d_out;
    float* ws  = (float*)d_ws;

    float* h    = ws + 0L*NCP;
    float* v    = ws + 1L*NCP;
    float* magg = ws + 2L*NCP;
    float* zg   = ws + 3L*NCP;   // conv: z-gate | attn: gated[9] (zg..rhg = 3 NCP)
    float* rg   = ws + 4L*NCP;
    float* rhg  = ws + 5L*NCP;
    float* hcmb = ws + 6L*NCP;   // hc (GRU)
    float* S    = ws + 7L*NCP;

    float* Mb9f   = S;                        // attn: 9*CP bf16 | conv: partials
    float* hp16f  = S + 7962624;
    float* hcp16f = hp16f + 884736;
    float* t16f   = hcp16f + 884736;
    float* ti16f  = t16f + 884736;
    float* wbase  = S + 11501568;
    bf16* Wint_t   = (bf16*)wbase;
    bf16* Wintra_t = Wint_t + 65536;
    bf16* gatew16  = Wint_t + 131072;
    bf16* cw16     = (bf16*)(wbase + 98304);  // 1024 x 4608 bf16
    bf16* inpad    = (bf16*)(wbase + 98304 + 2359296);
    float* maskp   = wbase + 98304 + 2359296 + 1929216;

    bf16* Mb9    = (bf16*)Mb9f;
    bf16* hp16   = (bf16*)hp16f;
    bf16* hcp16  = (bf16*)hcp16f;
    bf16* t16    = (bf16*)t16f;
    bf16* ti16   = (bf16*)ti16f;
    float* hc    = hcmb;
    float* gated = zg;                        // 9*CP fp32 = zg+rg+rhg
    float* cpart = Mb9f;

    dim3 b256(256);

    hipMemsetAsync(inpad, 0, 3858432*sizeof(bf16), stream);
    backbone_k<<<dim3(9,64,3), b256, 0, stream>>>(frames, backbone_w, backbone_b, v, h);
    convert_w_k<<<dim3(256), b256, 0, stream>>>(W_inter, W_intra, gate_w, Wint_t);
    convw_k<<<dim3(4608), b256, 0, stream>>>(Wz, cw16, 256*KC);
    convw_k<<<dim3(4608), b256, 0, stream>>>(Wr, cw16 + 256L*KC, 256*KC);
    convw_k<<<dim3(4608), b256, 0, stream>>>(Wh, cw16 + 512L*KC, 256*KC);
    convw_k<<<dim3(4608), b256, 0, stream>>>(ro_w1, cw16 + 768L*KC, 256*KC);

    for (int it = 0; it < 3; ++it) {
        // ---- attention phase ----
        prep_h_k<<<dim3(36,4,3), b256, 0, stream>>>(h, hcp16, hp16);
        mgemm_k<0,64><<<dim3(54,4,2), b256, 0, stream>>>(hp16, hp16, -1, Wint_t,
            nullptr, t16, nullptr, nullptr,
            6912,256, 256,256,256, 0, 0L,65536L,1769472L,0L, 2, 256, 0L);
        fattn_k<<<dim3(18,1,9), dim3(512), 0, stream>>>(t16, ti16, hp16, hcp16, Mb9);
        mgemm_k<2,64><<<dim3(2,36,9), b256, 0, stream>>>(gatew16, gatew16, -1,
            Mb9, gated, nullptr, Mb9, gate_b,
            256,2304, 256,256,PIX, 256, 0L,(long)CP,(long)CP,(long)CP,
            9, 256, 0L);
        gatesum_k<<<dim3(576,3), b256, 0, stream>>>(gated, magg);
        // ---- conv phase (implicit GEMM) ----
        padtr_k<<<dim3(36,4,3), b256, 0, stream>>>(magg, inpad, 0);
        padtr_k<<<dim3(36,4,3), b256, 0, stream>>>(h,    inpad, 256);
        cgemm2_k<<<dim3(54,8,2), b256, 0, stream>>>(inpad, cw16, cpart, 512);
        cred_k<1,1><<<dim3(13824), b256, 0, stream>>>(cpart, bz, br, zg, rhg, h, 512);
        padtr_k<<<dim3(36,4,3), b256, 0, stream>>>(rhg, inpad, 256);
        cgemm2_k<<<dim3(54,4,2), b256, 0, stream>>>(inpad, cw16 + 512L*KC, cpart, 256);
        cred_k<2,0><<<dim3(6912), b256, 0, stream>>>(cpart, bh, nullptr, hc, nullptr, nullptr, 256);
        hupd_k<<<dim3(6912), b256, 0, stream>>>(zg, hc, h);
    }

    // ---- readout ----
    padtr_k<<<dim3(36,4,3), b256, 0, stream>>>(h, inpad, 0);
    padtr_k<<<dim3(36,4,3), b256, 0, stream>>>(v, inpad, 256);
    cgemm2_k<<<dim3(54,4,2), b256, 0, stream>>>(inpad, cw16 + 768L*KC, cpart, 256);
    cred_k<3,0><<<dim3(6912), b256, 0, stream>>>(cpart, ro_b1, nullptr, zg, nullptr, nullptr, 256);
    maskpart_k<<<dim3(27,8), b256, 0, stream>>>(zg, ro_w2, maskp);
    maskred_k<<<dim3(27), b256, 0, stream>>>(maskp, ro_b2, out);
}

// Round 8
// 1153.329 us; speedup vs baseline: 1.4373x; 1.4373x over previous
//
#include <hip/hip_runtime.h>
#include <hip/hip_bf16.h>
#include <math.h>

#define PIX 2304
#define CCH 256
#define CP  589824      // CCH*PIX
#define NCP 1769472     // 3*CP
#define KC  4608        // conv K = 512*9
#define PADR 2512       // padded rows per image

typedef __hip_bfloat16 bf16;
typedef __attribute__((ext_vector_type(8))) short bf16x8;
typedef __attribute__((ext_vector_type(4))) float f32x4;

__device__ __forceinline__ float sigmoidf_(float x){ return 1.f/(1.f+__expf(-x)); }

__device__ __forceinline__ void gl_lds16(const bf16* g, bf16* lds){
    __builtin_amdgcn_global_load_lds(
        (const __attribute__((address_space(1))) void*)g,
        (__attribute__((address_space(3))) void*)lds, 16, 0, 0);
}
#define FENCE() asm volatile("" ::: "memory")

// =======================================================================
// Fused flash attention over 9 (i,j) pairs. Q = t_i (ti_i on diagonal),
// K = hp_j (P x C), V^T = hcp_j (C x P), both staged in dbuf LDS.
// 256 thr (4 waves), QBLK=64 (16 q-rows/wave), KVBLK=32.
// LDS = 32KB(Ks) + 32KB(Vs) + 4KB(Ps) = 68KB -> 2 blocks/CU; grid 324.
// Counted-vmcnt pipeline: stage(t+1) 8 loads; vmcnt(8) waits stage(t).
// =======================================================================
__global__ __launch_bounds__(256) void fattn_k(
    const bf16* __restrict__ T, const bf16* __restrict__ Ti,
    const bf16* __restrict__ Khp, const bf16* __restrict__ Vcp,
    bf16* __restrict__ Ob)
{
    __shared__ bf16 Ks[2][32*256];   // [kv][d], 32 chunks/row, swz rr&7
    __shared__ bf16 Vs[2][256*32];   // [c][kv], 4 chunks/row, swz (rr>>2)&3
    __shared__ bf16 Ps[4][512];      // per-wave P 16x32, chunk-major
    const int z = blockIdx.z, i = z/3, j = z%3;
    const bf16* Q  = ((i==j)? Ti : T) + (long)i*CP;
    const bf16* Kp = Khp + (long)j*CP;
    const bf16* Vp = Vcp + (long)j*CP;
    const int tid = threadIdx.x, l = tid & 63, w = tid >> 6;
    const int q0 = blockIdx.x*64;

    bf16x8 qf[8];
    {
        const bf16* qr = Q + (long)(q0 + w*16 + (l&15))*256 + (l>>4)*8;
        #pragma unroll
        for (int ks=0; ks<8; ++ks) qf[ks] = *(const bf16x8*)(qr + ks*32);
    }
    f32x4 oacc[16];
    #pragma unroll
    for (int nf=0; nf<16; ++nf) oacc[nf] = (f32x4){0.f,0.f,0.f,0.f};
    float mrun[4] = {-3e38f,-3e38f,-3e38f,-3e38f};
    float lrun[4] = {0.f,0.f,0.f,0.f};

    auto stage = [&](int buf, int t){
        const int kq = t*32;
        #pragma unroll
        for (int u=0; u<4; ++u){            // K tile: 32 kv-rows x 256 d
            int idx = u*256 + tid;
            int rr = idx>>5, cc = idx&31;
            gl_lds16(Kp + (long)(kq+rr)*256 + ((cc ^ (rr&7))<<3),
                     &Ks[buf][(u*256 + (tid & ~63))*8]);
        }
        #pragma unroll
        for (int u=0; u<4; ++u){            // V^T tile: 256 c-rows x 32 kv
            int idx = u*256 + tid;
            int rr = idx>>2, cc = idx&3;
            gl_lds16(Vp + (long)rr*2304 + kq + ((cc ^ ((rr>>2)&3))<<3),
                     &Vs[buf][(u*256 + (tid & ~63))*8]);
        }
    };

    stage(0, 0);
    int cur = 0;
    for (int t=0; t<72; ++t){
        if (t+1 < 72){
            stage(cur^1, t+1);
            asm volatile("s_waitcnt vmcnt(8)" ::: "memory");
        } else {
            asm volatile("s_waitcnt vmcnt(0)" ::: "memory");
        }
        __builtin_amdgcn_s_barrier();
        FENCE();

        // ---- QK^T: S[16 q-rows][32 kv] per wave ----
        f32x4 sacc[2];
        sacc[0] = (f32x4){0.f,0.f,0.f,0.f};
        sacc[1] = (f32x4){0.f,0.f,0.f,0.f};
        __builtin_amdgcn_s_setprio(1);
        #pragma unroll
        for (int ks=0; ks<8; ++ks){
            #pragma unroll
            for (int nf=0; nf<2; ++nf){
                int row = nf*16 + (l&15);
                int phys = (ks*4 + (l>>4)) ^ (row&7);
                bf16x8 b = *(const bf16x8*)&Ks[cur][row*256 + phys*8];
                sacc[nf] = __builtin_amdgcn_mfma_f32_16x16x32_bf16(qf[ks], b, sacc[nf], 0,0,0);
            }
        }
        __builtin_amdgcn_s_setprio(0);

        // ---- online softmax (lane tracks q-rows (l>>4)*4 + r) ----
        float alpha[4];
        #pragma unroll
        for (int r=0; r<4; ++r){
            float v = fmaxf(sacc[0][r], sacc[1][r]);
            v = fmaxf(v, __shfl_xor(v,1)); v = fmaxf(v, __shfl_xor(v,2));
            v = fmaxf(v, __shfl_xor(v,4)); v = fmaxf(v, __shfl_xor(v,8));
            float mn = fmaxf(mrun[r], v);
            alpha[r] = __expf(mrun[r] - mn);
            mrun[r] = mn;
            float rs = 0.f;
            #pragma unroll
            for (int nf=0; nf<2; ++nf){
                float p = __expf(sacc[nf][r] - mn);
                sacc[nf][r] = p; rs += p;
            }
            rs += __shfl_xor(rs,1); rs += __shfl_xor(rs,2);
            rs += __shfl_xor(rs,4); rs += __shfl_xor(rs,8);
            lrun[r] = lrun[r]*alpha[r] + rs;
        }
        // ---- P -> LDS (per-wave, chunk-major: elem=(col>>3)*128+row*8+(col&7)) ----
        #pragma unroll
        for (int nf=0; nf<2; ++nf)
            #pragma unroll
            for (int r=0; r<4; ++r){
                int row = (l>>4)*4 + r;
                int col = nf*16 + (l&15);
                Ps[w][(col>>3)*128 + row*8 + (col&7)] = __float2bfloat16(sacc[nf][r]);
            }
        FENCE();
        // ---- rescale O ----
        #pragma unroll
        for (int nf=0; nf<16; ++nf)
            #pragma unroll
            for (int r=0; r<4; ++r) oacc[nf][r] *= alpha[r];
        // ---- PV: O[16 q][256 c] += P * V (one k=32 step) ----
        bf16x8 pa = *(const bf16x8*)&Ps[w][(l>>4)*128 + (l&15)*8];
        __builtin_amdgcn_s_setprio(1);
        #pragma unroll
        for (int nf=0; nf<16; ++nf){
            int row = nf*16 + (l&15);
            int phys = (l>>4) ^ ((row>>2)&3);
            bf16x8 bv = *(const bf16x8*)&Vs[cur][row*32 + phys*8];
            oacc[nf] = __builtin_amdgcn_mfma_f32_16x16x32_bf16(pa, bv, oacc[nf], 0,0,0);
        }
        __builtin_amdgcn_s_setprio(0);
        FENCE();
        __builtin_amdgcn_s_barrier();   // buf consumed -> restageable next iter
        FENCE();
        cur ^= 1;
    }

    #pragma unroll
    for (int r=0; r<4; ++r) lrun[r] = 1.f / lrun[r];
    bf16* ob = Ob + (long)z*CP;
    const int prow0 = q0 + w*16 + (l>>4)*4;
    #pragma unroll
    for (int nf=0; nf<16; ++nf){
        int c = nf*16 + (l&15);
        #pragma unroll
        for (int r=0; r<4; ++r)
            ob[(long)(prow0+r)*256 + c] = __float2bfloat16(oacc[nf][r]*lrun[r]);
    }
}

// =======================================================================
// Unified bf16 MFMA GEMM, BT layout, XOR-swizzled LDS, counted-vmcnt dbuf.
// EPI 0: bf16 out.  EPI 2: fp32 sigmoid(acc+bias0[m]) * aux[n*auxld+m].
// =======================================================================
template<int EPI, int BN>
__global__ __launch_bounds__(256) void mgemm_k(
    const bf16* __restrict__ A0, const bf16* __restrict__ A1, int diagz,
    const bf16* __restrict__ B,
    float* __restrict__ o0, bf16* __restrict__ ob,
    const bf16* __restrict__ aux, const float* __restrict__ bias0,
    int M, int N, int lda, int ldb, int ldc, int auxld,
    long bsA, long bsB, long bsC, long bsAux,
    int nzJ, int Ksub, long bsKc)
{
    __shared__ bf16 As[2][128*64];
    __shared__ bf16 Bs[2][BN*64];
    const int z = blockIdx.z;
    const int jz = z % nzJ, kc = z / nzJ;
    const bf16* Ap = ((jz==diagz)?A1:A0) + jz*bsA + (long)blockIdx.x*128*lda;
    const bf16* Bp = B + jz*bsB + (long)blockIdx.y*BN*ldb;
    const int tid = threadIdx.x, l = tid & 63;
    const int wvu = tid & ~63;
    const int wr = tid>>7, wc = (tid>>6)&1;
    constexpr int NF = BN/32;
    f32x4 acc[4][NF];
    #pragma unroll
    for (int i=0;i<4;++i)
        #pragma unroll
        for (int j=0;j<NF;++j) acc[i][j] = (f32x4){0.f,0.f,0.f,0.f};

    auto stage = [&](int buf, int kb){
        #pragma unroll
        for (int u=0;u<4;++u){
            int idx = u*256 + tid;
            int row = idx>>3, g = (idx&7) ^ (row&7);
            gl_lds16(Ap + (long)row*lda + kb + g*8, &As[buf][(u*256+wvu)*8]);
        }
        #pragma unroll
        for (int u=0;u<BN/32;++u){
            int idx = u*256 + tid;
            int row = idx>>3, g = (idx&7) ^ (row&7);
            gl_lds16(Bp + (long)row*ldb + kb + g*8, &Bs[buf][(u*256+wvu)*8]);
        }
    };

    const int kbeg = kc*Ksub;
    const int nk = Ksub >> 6;
    stage(0, kbeg);
    int cur = 0;
    for (int t=0; t<nk; ++t){
        if (t+1 < nk){
            stage(cur^1, kbeg + (t+1)*64);
            if constexpr (BN==64) asm volatile("s_waitcnt vmcnt(6)" ::: "memory");
            else                  asm volatile("s_waitcnt vmcnt(8)" ::: "memory");
        } else {
            asm volatile("s_waitcnt vmcnt(0)" ::: "memory");
        }
        __builtin_amdgcn_s_barrier();
        FENCE();
        #pragma unroll
        for (int ks=0; ks<64; ks+=32){
            bf16x8 af[4], bfr[NF];
            #pragma unroll
            for (int i=0;i<4;++i){
                int row = wr*64 + i*16 + (l&15);
                af[i] = *(const bf16x8*)&As[cur][row*64 + ((((ks>>3)+(l>>4)) ^ (row&7))<<3)];
            }
            #pragma unroll
            for (int j=0;j<NF;++j){
                int row = wc*(BN/2) + j*16 + (l&15);
                bfr[j] = *(const bf16x8*)&Bs[cur][row*64 + ((((ks>>3)+(l>>4)) ^ (row&7))<<3)];
            }
            #pragma unroll
            for (int i=0;i<4;++i)
                #pragma unroll
                for (int j=0;j<NF;++j)
                    acc[i][j] = __builtin_amdgcn_mfma_f32_16x16x32_bf16(af[i], bfr[j], acc[i][j], 0,0,0);
        }
        FENCE();
        __builtin_amdgcn_s_barrier();
        FENCE();
        cur ^= 1;
    }

    const int mb = blockIdx.x*128 + wr*64, nb = blockIdx.y*BN + wc*(BN/2);
    #pragma unroll
    for (int i=0;i<4;++i)
        #pragma unroll
        for (int j=0;j<NF;++j){
            int gm0 = mb + i*16 + ((l>>4)<<2);
            int gn  = nb + j*16 + (l&15);
            #pragma unroll
            for (int r=0;r<4;++r){
                int gm = gm0 + r;
                float vacc = acc[i][j][r];
                if (EPI==0){
                    ob[jz*bsC + (long)gm*ldc + gn] = __float2bfloat16(vacc);
                } else {
                    float g = sigmoidf_(vacc + bias0[gm]);
                    float mv = __bfloat162float(aux[jz*bsAux + (long)gn*auxld + gm]);
                    o0[jz*bsC + (long)gm*ldc + gn] = g*mv;
                }
            }
        }
}

// =======================================================================
// Implicit-GEMM 3x3 conv, counted-vmcnt dbuf pipeline.
// =======================================================================
__global__ __launch_bounds__(256) void cgemm2_k(
    const bf16* __restrict__ inpad, const bf16* __restrict__ W,
    float* __restrict__ part, int N)
{
    __shared__ bf16 As[2][128*64];
    __shared__ bf16 Bs[2][64*64];
    const int tid = threadIdx.x, l = tid & 63, wvu = tid & ~63;
    const int wr = tid>>7, wc = (tid>>6)&1;
    const int bx = blockIdx.x, by = blockIdx.y, kc = blockIdx.z;
    const int img = bx/18, m0 = (bx - img*18)*128;
    const bf16* Ab = inpad + (long)img*PADR*512;
    const bf16* Bb = W + (long)by*64*KC;
    f32x4 acc[4][2];
    #pragma unroll
    for (int i=0;i<4;++i){ acc[i][0]=(f32x4){0,0,0,0}; acc[i][1]=(f32x4){0,0,0,0}; }

    auto stageA = [&](int buf, int k0){
        int tap = k0 >> 9, ci0 = k0 & 511;
        int dy = tap/3, dx = tap - 3*dy;
        int shift = (dy-1)*50 + (dx-1);
        #pragma unroll
        for (int u=0;u<4;++u){
            int idx = u*256 + tid;
            int row = idx>>3;
            int om = m0 + row;
            int prow = om + 2*(om/48) + 51 + shift;
            int g = (idx&7) ^ (row&7);
            gl_lds16(Ab + (long)prow*512 + ci0 + g*8, &As[buf][(u*256+wvu)*8]);
        }
    };
    auto stageB = [&](int buf, int k0){
        #pragma unroll
        for (int u=0;u<2;++u){
            int idx = u*256 + tid;
            int row = idx>>3;
            int g = (idx&7) ^ (row&7);
            gl_lds16(Bb + (long)row*KC + k0 + g*8, &Bs[buf][(u*256+wvu)*8]);
        }
    };

    const int kbeg = kc*2304;
    stageA(0, kbeg); stageB(0, kbeg);
    int cur = 0;
    for (int t=0; t<36; ++t){
        if (t+1 < 36){
            stageA(cur^1, kbeg+(t+1)*64); stageB(cur^1, kbeg+(t+1)*64);
            asm volatile("s_waitcnt vmcnt(6)" ::: "memory");
        } else {
            asm volatile("s_waitcnt vmcnt(0)" ::: "memory");
        }
        __builtin_amdgcn_s_barrier();
        FENCE();
        #pragma unroll
        for (int ks=0; ks<64; ks+=32){
            bf16x8 af[4], bfr[2];
            #pragma unroll
            for (int i=0;i<4;++i){
                int row = wr*64 + i*16 + (l&15);
                af[i] = *(const bf16x8*)&As[cur][row*64 + ((((ks>>3)+(l>>4)) ^ (row&7))<<3)];
            }
            #pragma unroll
            for (int j=0;j<2;++j){
                int row = wc*32 + j*16 + (l&15);
                bfr[j] = *(const bf16x8*)&Bs[cur][row*64 + ((((ks>>3)+(l>>4)) ^ (row&7))<<3)];
            }
            #pragma unroll
            for (int i=0;i<4;++i)
                #pragma unroll
                for (int j=0;j<2;++j)
                    acc[i][j] = __builtin_amdgcn_mfma_f32_16x16x32_bf16(af[i], bfr[j], acc[i][j], 0,0,0);
        }
        FENCE();
        __builtin_amdgcn_s_barrier();
        FENCE();
        cur ^= 1;
    }

    float* pbase = part + (long)kc*N*6912 + (long)img*2304;
    #pragma unroll
    for (int i=0;i<4;++i)
        #pragma unroll
        for (int j=0;j<2;++j){
            int gm0 = m0 + wr*64 + i*16 + ((l>>4)<<2);
            int gn  = by*64 + wc*32 + j*16 + (l&15);
            *(f32x4*)&pbase[(long)gn*6912 + gm0] = acc[i][j];
        }
}

// ---- split-K reduce + bias + activation; DUAL r-branch fuses *h (rh) ----
template<int ACT, int DUAL>
__global__ __launch_bounds__(256) void cred_k(const float* __restrict__ part,
        const float* __restrict__ b0, const float* __restrict__ b1,
        float* __restrict__ o0, float* __restrict__ o1,
        const float* __restrict__ hmul, int N)
{
    int id = blockIdx.x*256 + threadIdx.x;
    int c = id / 6912, g = id - c*6912;
    int img = g / 2304, p = g - img*2304;
    float v = part[id] + part[id + (long)N*6912];
    if (DUAL && c >= 256){
        int co = c - 256;
        long oidx = (long)img*CP + (long)co*PIX + p;
        o1[oidx] = sigmoidf_(v + b1[co]) * hmul[oidx];
    } else {
        float r = v + b0[c];
        if (ACT==1) r = sigmoidf_(r);
        else if (ACT==2) r = tanhf(r);
        else r = fmaxf(r, 0.f);
        o0[(long)img*CP + (long)c*PIX + p] = r;
    }
}

__global__ __launch_bounds__(256) void padtr_k(const float* __restrict__ src,
        bf16* __restrict__ dst, int cofs)
{
    __shared__ float tile[64][65];
    const int img = blockIdx.z, p0 = blockIdx.x*64, c0 = blockIdx.y*64;
    const int t = threadIdx.x, tx = t&63, tq = t>>6;
    const float* s = src + (long)img*CP;
    #pragma unroll
    for (int u=0;u<16;++u){
        int r = tq + u*4;
        tile[r][tx] = s[(long)(c0+r)*PIX + p0 + tx];
    }
    __syncthreads();
    bf16* d = dst + (long)img*PADR*512 + cofs + c0;
    #pragma unroll
    for (int u=0;u<16;++u){
        int pl = tq + u*4;
        int p = p0 + pl;
        int prow = p + 2*(p/48) + 51;
        d[(long)prow*512 + tx] = __float2bfloat16(tile[tx][pl]);
    }
}

__global__ __launch_bounds__(256) void convw_k(const float* __restrict__ src,
        bf16* __restrict__ dst, int total)
{
    int idx = blockIdx.x*256 + threadIdx.x;
    if (idx >= total) return;
    int co = idx / KC, r = idx - co*KC;
    int tap = r >> 9, ci = r & 511;
    dst[idx] = __float2bfloat16(src[(long)co*KC + ci*9 + tap]);
}

__global__ __launch_bounds__(256) void prep_h_k(const float* __restrict__ h,
        bf16* __restrict__ hcp, bf16* __restrict__ hp)
{
    __shared__ float tile[64][65];
    const int i = blockIdx.z, p0 = blockIdx.x*64, c0 = blockIdx.y*64;
    const int t = threadIdx.x, tx = t&63, tq = t>>6;
    const float* src = h + (long)i*CP;
    #pragma unroll
    for (int s=0;s<16;++s){
        int r = tq + s*4;
        float v = src[(long)(c0+r)*PIX + p0 + tx];
        tile[r][tx] = v;
        hcp[(long)i*CP + (long)(c0+r)*PIX + p0 + tx] = __float2bfloat16(v);
    }
    __syncthreads();
    #pragma unroll
    for (int s=0;s<16;++s){
        int r = tq + s*4;
        hp[(long)i*CP + (long)(p0+r)*256 + c0 + tx] = __float2bfloat16(tile[tx][r]);
    }
}

__global__ __launch_bounds__(256) void convert_w_k(const float* __restrict__ wint,
    const float* __restrict__ wintra, const float* __restrict__ gw, bf16* __restrict__ o)
{
    int t = blockIdx.x*256 + threadIdx.x;
    int d = t >> 8, c = t & 255;
    o[t]          = __float2bfloat16(wint[c*256 + d]);
    o[65536 + t]  = __float2bfloat16(wintra[c*256 + d]);
    o[131072 + t] = __float2bfloat16(gw[t]);
}

__global__ __launch_bounds__(256) void gatesum_k(const float* __restrict__ g, float* __restrict__ out)
{
    int x = blockIdx.x*256 + threadIdx.x;
    int i = blockIdx.y;
    const float* gi = g + (long)i*3*CP;
    float4 a = ((const float4*)gi)[x];
    float4 b = ((const float4*)gi)[x + CP/4];
    float4 c = ((const float4*)gi)[x + CP/2];
    float4 r; r.x=a.x+b.x+c.x; r.y=a.y+b.y+c.y; r.z=a.z+b.z+c.z; r.w=a.w+b.w+c.w;
    ((float4*)(out + (long)i*CP))[x] = r;
}

__global__ __launch_bounds__(256) void backbone_k(
    const float* __restrict__ frames, const float* __restrict__ W,
    const float* __restrict__ bias, float* __restrict__ v, float* __restrict__ h)
{
    __shared__ float wl[3*64*4];
    const int n = blockIdx.z, o0 = blockIdx.y * 4;
    const int p = blockIdx.x * 256 + threadIdx.x;
    const int y = p / 48, x = p % 48;
    for (int e = threadIdx.x; e < 768; e += 256) {
        int o_sel = e / 192, rem = e % 192, ci = rem / 64, k = rem % 64;
        wl[(ci*64 + k)*4 + o_sel] = W[((long)(o0 + o_sel)*3 + ci)*64 + k];
    }
    __syncthreads();
    float acc[4] = {0.f,0.f,0.f,0.f};
    for (int ci = 0; ci < 3; ++ci) {
        const float* src = frames + (((long)n*3 + ci)*384) * 384;
        #pragma unroll
        for (int k = 0; k < 64; ++k) {
            int ky = k >> 3, kx = k & 7;
            float iv = src[(8*y + ky)*384 + 8*x + kx];
            float4 w = ((const float4*)wl)[ci*64 + k];
            acc[0] += iv*w.x; acc[1] += iv*w.y; acc[2] += iv*w.z; acc[3] += iv*w.w;
        }
    }
    #pragma unroll
    for (int oo = 0; oo < 4; ++oo) {
        float r = fmaxf(acc[oo] + bias[o0 + oo], 0.f);
        long idx = ((long)n*CCH + o0 + oo)*PIX + p;
        v[idx] = r; h[idx] = r;
    }
}

__global__ __launch_bounds__(256) void hupd_k(const float* __restrict__ zg, const float* __restrict__ hc,
                                              float* __restrict__ h)
{
    int idx = blockIdx.x*256 + threadIdx.x;
    float z = zg[idx];
    h[idx] = (1.f - z)*h[idx] + z*hc[idx];
}

__global__ __launch_bounds__(256) void maskpart_k(const float* __restrict__ yin,
        const float* __restrict__ W, float* __restrict__ part)
{
    __shared__ float wl[288];
    const int cb = blockIdx.y * 32;
    for (int e = threadIdx.x; e < 288; e += 256) wl[e] = W[cb*9 + e];
    __syncthreads();
    int id = blockIdx.x*256 + threadIdx.x;
    int n = id / PIX, p = id - n*PIX;
    int y = p / 48, x = p % 48;
    float acc = 0.f;
    for (int ci = 0; ci < 32; ++ci) {
        const float* src = yin + ((long)n*CCH + cb + ci)*PIX;
        #pragma unroll
        for (int dy = 0; dy < 3; ++dy) {
            int yy = y + dy - 1;
            #pragma unroll
            for (int dx = 0; dx < 3; ++dx) {
                int xx = x + dx - 1;
                float iv = (yy >= 0 && yy < 48 && xx >= 0 && xx < 48) ? src[yy*48 + xx] : 0.f;
                acc += iv * wl[ci*9 + dy*3 + dx];
            }
        }
    }
    part[(long)blockIdx.y*(3*PIX) + id] = acc;
}

__global__ __launch_bounds__(256) void maskred_k(const float* __restrict__ part,
        const float* __restrict__ bias, float* __restrict__ out)
{
    int id = blockIdx.x*256 + threadIdx.x;
    float acc = bias[0];
    #pragma unroll
    for (int s = 0; s < 8; ++s) acc += part[(long)s*(3*PIX) + id];
    out[id] = acc;
}

extern "C" void kernel_launch(void* const* d_in, const int* in_sizes, int n_in,
                              void* d_out, int out_size, void* d_ws, size_t ws_size,
                              hipStream_t stream)
{
    const float* frames     = (const float*)d_in[0];
    const float* backbone_w = (const float*)d_in[1];
    const float* backbone_b = (const float*)d_in[2];
    const float* W_intra    = (const float*)d_in[3];
    const float* W_inter    = (const float*)d_in[4];
    const float* gate_w     = (const float*)d_in[5];
    const float* gate_b     = (const float*)d_in[6];
    const float* Wz         = (const float*)d_in[7];
    const float* bz         = (const float*)d_in[8];
    const float* Wr         = (const float*)d_in[9];
    const float* br         = (const float*)d_in[10];
    const float* Wh         = (const float*)d_in[11];
    const float* bh         = (const float*)d_in[12];
    const float* ro_w1      = (const float*)d_in[13];
    const float* ro_b1      = (const float*)d_in[14];
    const float* ro_w2      = (const float*)d_in[15];
    const float* ro_b2      = (const float*)d_in[16];
    float* out = (float*)d_out;
    float* ws  = (float*)d_ws;

    float* h    = ws + 0L*NCP;
    float* v    = ws + 1L*NCP;
    float* magg = ws + 2L*NCP;
    float* zg   = ws + 3L*NCP;   // conv: z-gate | attn: gated[9] (zg..rhg = 3 NCP)
    float* rg   = ws + 4L*NCP;
    float* rhg  = ws + 5L*NCP;
    float* hcmb = ws + 6L*NCP;   // hc (GRU)
    float* S    = ws + 7L*NCP;

    float* Mb9f   = S;                        // attn: 9*CP bf16 | conv: partials
    float* hp16f  = S + 7962624;
    float* hcp16f = hp16f + 884736;
    float* t16f   = hcp16f + 884736;
    float* ti16f  = t16f + 884736;
    float* wbase  = S + 11501568;
    bf16* Wint_t   = (bf16*)wbase;
    bf16* Wintra_t = Wint_t + 65536;
    bf16* gatew16  = Wint_t + 131072;
    bf16* cw16     = (bf16*)(wbase + 98304);  // 1024 x 4608 bf16
    bf16* inpad    = (bf16*)(wbase + 98304 + 2359296);
    float* maskp   = wbase + 98304 + 2359296 + 1929216;

    bf16* Mb9    = (bf16*)Mb9f;
    bf16* hp16   = (bf16*)hp16f;
    bf16* hcp16  = (bf16*)hcp16f;
    bf16* t16    = (bf16*)t16f;
    bf16* ti16   = (bf16*)ti16f;
    float* hc    = hcmb;
    float* gated = zg;                        // 9*CP fp32 = zg+rg+rhg
    float* cpart = Mb9f;

    dim3 b256(256);

    hipMemsetAsync(inpad, 0, 3858432*sizeof(bf16), stream);
    backbone_k<<<dim3(9,64,3), b256, 0, stream>>>(frames, backbone_w, backbone_b, v, h);
    convert_w_k<<<dim3(256), b256, 0, stream>>>(W_inter, W_intra, gate_w, Wint_t);
    convw_k<<<dim3(4608), b256, 0, stream>>>(Wz, cw16, 256*KC);
    convw_k<<<dim3(4608), b256, 0, stream>>>(Wr, cw16 + 256L*KC, 256*KC);
    convw_k<<<dim3(4608), b256, 0, stream>>>(Wh, cw16 + 512L*KC, 256*KC);
    convw_k<<<dim3(4608), b256, 0, stream>>>(ro_w1, cw16 + 768L*KC, 256*KC);

    for (int it = 0; it < 3; ++it) {
        // ---- attention phase ----
        prep_h_k<<<dim3(36,4,3), b256, 0, stream>>>(h, hcp16, hp16);
        mgemm_k<0,64><<<dim3(54,4,2), b256, 0, stream>>>(hp16, hp16, -1, Wint_t,
            nullptr, t16, nullptr, nullptr,
            6912,256, 256,256,256, 0, 0L,65536L,1769472L,0L, 2, 256, 0L);
        fattn_k<<<dim3(36,1,9), b256, 0, stream>>>(t16, ti16, hp16, hcp16, Mb9);
        mgemm_k<2,64><<<dim3(2,36,9), b256, 0, stream>>>(gatew16, gatew16, -1,
            Mb9, gated, nullptr, Mb9, gate_b,
            256,2304, 256,256,PIX, 256, 0L,(long)CP,(long)CP,(long)CP,
            9, 256, 0L);
        gatesum_k<<<dim3(576,3), b256, 0, stream>>>(gated, magg);
        // ---- conv phase (implicit GEMM) ----
        padtr_k<<<dim3(36,4,3), b256, 0, stream>>>(magg, inpad, 0);
        padtr_k<<<dim3(36,4,3), b256, 0, stream>>>(h,    inpad, 256);
        cgemm2_k<<<dim3(54,8,2), b256, 0, stream>>>(inpad, cw16, cpart, 512);
        cred_k<1,1><<<dim3(13824), b256, 0, stream>>>(cpart, bz, br, zg, rhg, h, 512);
        padtr_k<<<dim3(36,4,3), b256, 0, stream>>>(rhg, inpad, 256);
        cgemm2_k<<<dim3(54,4,2), b256, 0, stream>>>(inpad, cw16 + 512L*KC, cpart, 256);
        cred_k<2,0><<<dim3(6912), b256, 0, stream>>>(cpart, bh, nullptr, hc, nullptr, nullptr, 256);
        hupd_k<<<dim3(6912), b256, 0, stream>>>(zg, hc, h);
    }

    // ---- readout ----
    padtr_k<<<dim3(36,4,3), b256, 0, stream>>>(h, inpad, 0);
    padtr_k<<<dim3(36,4,3), b256, 0, stream>>>(v, inpad, 256);
    cgemm2_k<<<dim3(54,4,2), b256, 0, stream>>>(inpad, cw16 + 768L*KC, cpart, 256);
    cred_k<3,0><<<dim3(6912), b256, 0, stream>>>(cpart, ro_b1, nullptr, zg, nullptr, nullptr, 256);
    maskpart_k<<<dim3(27,8), b256, 0, stream>>>(zg, ro_w2, maskp);
    maskred_k<<<dim3(27), b256, 0, stream>>>(maskp, ro_b2, out);
}

// Round 9
// 949.372 us; speedup vs baseline: 1.7461x; 1.2148x over previous
//
#include <hip/hip_runtime.h>
#include <hip/hip_bf16.h>
#include <math.h>

#define PIX 2304
#define CCH 256
#define CP  589824      // CCH*PIX
#define NCP 1769472     // 3*CP
#define KC  4608        // conv K = 512*9
#define PADR 2512       // padded rows per image

typedef __hip_bfloat16 bf16;
typedef __attribute__((ext_vector_type(8))) short bf16x8;
typedef __attribute__((ext_vector_type(4))) float f32x4;

__device__ __forceinline__ float sigmoidf_(float x){ return 1.f/(1.f+__expf(-x)); }

__device__ __forceinline__ void gl_lds16(const bf16* g, bf16* lds){
    __builtin_amdgcn_global_load_lds(
        (const __attribute__((address_space(1))) void*)g,
        (__attribute__((address_space(3))) void*)lds, 16, 0, 0);
}
#define FENCE() asm volatile("" ::: "memory")

__device__ __forceinline__ float bperm_f(int srcLane, float v){
    return __int_as_float(__builtin_amdgcn_ds_bpermute(srcLane<<2, __float_as_int(v)));
}
__device__ __forceinline__ unsigned packbf(float lo, float hi){
    bf16 a = __float2bfloat16(lo), b = __float2bfloat16(hi);
    return (unsigned)(*(unsigned short*)&a) | ((unsigned)(*(unsigned short*)&b)<<16);
}

// =======================================================================
// Fused flash attention, 9 (i,j) pairs. SWAPPED QK^T (S^T = K*Q) so softmax
// is in-lane per q-column; defer-max (THR=8) skips O-rescale; P repacked to
// A-frag layout via packed-u32 LDS roundtrip (XOR-chunk swizzled).
// 512 thr (8 waves), QBLK=128 (16 q/wave), KVBLK=64, K+V dbuf LDS 144KB.
// =======================================================================
__global__ __launch_bounds__(512) void fattn_k(
    const bf16* __restrict__ T, const bf16* __restrict__ Ti,
    const bf16* __restrict__ Khp, const bf16* __restrict__ Vcp,
    bf16* __restrict__ Ob)
{
    __shared__ bf16 Ks[2][64*256];   // [kv][d], 32 chunks/row, swz ^(row&7)
    __shared__ bf16 Vs[2][256*64];   // [c][kv], 8 chunks/row, swz ^(row&7)
    __shared__ unsigned Ps[8][512];  // per-wave P 16q x 64kv bf16, XOR-chunk
    const int z = blockIdx.z, i = z/3, j = z%3;
    const bf16* Q  = ((i==j)? Ti : T) + (long)i*CP;
    const bf16* Kp = Khp + (long)j*CP;
    const bf16* Vp = Vcp + (long)j*CP;
    const int tid = threadIdx.x, l = tid & 63, w = tid >> 6;
    const int g = l>>4, m = l&15;
    const int q0 = blockIdx.x*128;

    // Q fragments (same data layout as always; used as B-operand now)
    bf16x8 qf[8];
    {
        const bf16* qr = Q + (long)(q0 + w*16 + m)*256 + g*8;
        #pragma unroll
        for (int ks=0; ks<8; ++ks) qf[ks] = *(const bf16x8*)(qr + ks*32);
    }
    f32x4 oacc[16];
    #pragma unroll
    for (int nf=0; nf<16; ++nf) oacc[nf] = (f32x4){0.f,0.f,0.f,0.f};
    float mrun = -3e38f;   // running max for q-col = m (this lane's column)
    float lrun = 0.f;

    auto stage = [&](int buf, int t){
        const int kq = t*64;
        #pragma unroll
        for (int u=0; u<4; ++u){            // K tile: 64 kv x 256 d
            int idx = u*512 + tid;
            int rr = idx>>5, cc = idx&31;
            gl_lds16(Kp + (long)(kq+rr)*256 + ((cc ^ (rr&7))<<3),
                     &Ks[buf][(u*512 + (tid & ~63))*8]);
        }
        #pragma unroll
        for (int u=0; u<4; ++u){            // V^T tile: 256 c x 64 kv
            int idx = u*512 + tid;
            int rr = idx>>3, cc = idx&7;
            gl_lds16(Vp + (long)rr*2304 + kq + ((cc ^ (rr&7))<<3),
                     &Vs[buf][(u*512 + (tid & ~63))*8]);
        }
    };

    stage(0, 0);
    int cur = 0;
    char* pw = (char*)&Ps[w][0];
    for (int t=0; t<36; ++t){
        if (t+1 < 36){
            stage(cur^1, t+1);
            asm volatile("s_waitcnt vmcnt(8)" ::: "memory");
        } else {
            asm volatile("s_waitcnt vmcnt(0)" ::: "memory");
        }
        __builtin_amdgcn_s_barrier();
        FENCE();

        // ---- swapped QK^T: sacc[nf] = S^T[kv=nf*16+g*4+r][q=m] ----
        f32x4 sacc[4];
        #pragma unroll
        for (int nf=0; nf<4; ++nf) sacc[nf] = (f32x4){0.f,0.f,0.f,0.f};
        __builtin_amdgcn_s_setprio(1);
        #pragma unroll
        for (int ks=0; ks<8; ++ks){
            #pragma unroll
            for (int nf=0; nf<4; ++nf){
                int row = nf*16 + m;
                int phys = (ks*4 + g) ^ (row&7);
                bf16x8 kf = *(const bf16x8*)&Ks[cur][row*256 + phys*8];
                sacc[nf] = __builtin_amdgcn_mfma_f32_16x16x32_bf16(kf, qf[ks], sacc[nf], 0,0,0);
            }
        }
        __builtin_amdgcn_s_setprio(0);

        // ---- in-lane softmax for q-column m ----
        float pmax = -3e38f;
        #pragma unroll
        for (int nf=0; nf<4; ++nf)
            #pragma unroll
            for (int r=0; r<4; ++r) pmax = fmaxf(pmax, sacc[nf][r]);
        pmax = fmaxf(pmax, __shfl_xor(pmax, 16));
        pmax = fmaxf(pmax, __shfl_xor(pmax, 32));
        if (!__all(pmax - mrun <= 8.f)){
            float mn = fmaxf(mrun, pmax);
            float al = __expf(mrun - mn);
            mrun = mn;
            lrun *= al;
            float ar[4];
            #pragma unroll
            for (int r=0; r<4; ++r) ar[r] = bperm_f((l & 48) | (g*4 + r), al);
            #pragma unroll
            for (int nf=0; nf<16; ++nf)
                #pragma unroll
                for (int r=0; r<4; ++r) oacc[nf][r] *= ar[r];
        }
        float rs = 0.f;
        unsigned pk[4][2];
        #pragma unroll
        for (int nf=0; nf<4; ++nf){
            float p0 = __expf(sacc[nf][0] - mrun);
            float p1 = __expf(sacc[nf][1] - mrun);
            float p2 = __expf(sacc[nf][2] - mrun);
            float p3 = __expf(sacc[nf][3] - mrun);
            rs += (p0+p1) + (p2+p3);
            pk[nf][0] = packbf(p0, p1);
            pk[nf][1] = packbf(p2, p3);
        }
        rs += __shfl_xor(rs, 16);
        rs += __shfl_xor(rs, 32);
        lrun += rs;
        // ---- P -> LDS, packed u32, XOR-chunk layout [q=m][kv] ----
        #pragma unroll
        for (int nf=0; nf<4; ++nf)
            #pragma unroll
            for (int s=0; s<2; ++s){
                int ba = m*128 + ((nf*32 + g*8 + s*4) ^ ((m&7)<<4));
                *(unsigned*)(pw + ba) = pk[nf][s];
            }
        asm volatile("s_waitcnt lgkmcnt(0)" ::: "memory");
        __builtin_amdgcn_sched_barrier(0);
        // ---- PV: O[q][c] += P * V ----
        __builtin_amdgcn_s_setprio(1);
        #pragma unroll
        for (int ks2=0; ks2<2; ++ks2){
            bf16x8 pa = *(const bf16x8*)(pw + m*128 + ((ks2*64 + g*16) ^ ((m&7)<<4)));
            #pragma unroll
            for (int nf=0; nf<16; ++nf){
                int row = nf*16 + m;
                int phys = (ks2*4 + g) ^ (row&7);
                bf16x8 bv = *(const bf16x8*)&Vs[cur][row*64 + phys*8];
                oacc[nf] = __builtin_amdgcn_mfma_f32_16x16x32_bf16(pa, bv, oacc[nf], 0,0,0);
            }
        }
        __builtin_amdgcn_s_setprio(0);
        FENCE();
        __builtin_amdgcn_s_barrier();
        FENCE();
        cur ^= 1;
    }

    // ---- normalize + store: O rows q_o = g*4+r, cols c = nf*16+m ----
    float linv = 1.f / lrun;
    float li[4];
    #pragma unroll
    for (int r=0; r<4; ++r) li[r] = bperm_f((l & 48) | (g*4 + r), linv);
    bf16* ob = Ob + (long)z*CP;
    const int prow0 = q0 + w*16 + g*4;
    #pragma unroll
    for (int nf=0; nf<16; ++nf){
        int c = nf*16 + m;
        #pragma unroll
        for (int r=0; r<4; ++r)
            ob[(long)(prow0+r)*256 + c] = __float2bfloat16(oacc[nf][r]*li[r]);
    }
}

// =======================================================================
// Unified bf16 MFMA GEMM, BT layout, XOR-swizzled LDS, counted-vmcnt dbuf.
// EPI 0: bf16 out.  EPI 2: fp32 sigmoid(acc+bias0[m]) * aux[n*auxld+m].
// =======================================================================
template<int EPI, int BN>
__global__ __launch_bounds__(256) void mgemm_k(
    const bf16* __restrict__ A0, const bf16* __restrict__ A1, int diagz,
    const bf16* __restrict__ B,
    float* __restrict__ o0, bf16* __restrict__ ob,
    const bf16* __restrict__ aux, const float* __restrict__ bias0,
    int M, int N, int lda, int ldb, int ldc, int auxld,
    long bsA, long bsB, long bsC, long bsAux,
    int nzJ, int Ksub, long bsKc)
{
    __shared__ bf16 As[2][128*64];
    __shared__ bf16 Bs[2][BN*64];
    const int z = blockIdx.z;
    const int jz = z % nzJ, kc = z / nzJ;
    const bf16* Ap = ((jz==diagz)?A1:A0) + jz*bsA + (long)blockIdx.x*128*lda;
    const bf16* Bp = B + jz*bsB + (long)blockIdx.y*BN*ldb;
    const int tid = threadIdx.x, l = tid & 63;
    const int wvu = tid & ~63;
    const int wr = tid>>7, wc = (tid>>6)&1;
    constexpr int NF = BN/32;
    f32x4 acc[4][NF];
    #pragma unroll
    for (int i=0;i<4;++i)
        #pragma unroll
        for (int j=0;j<NF;++j) acc[i][j] = (f32x4){0.f,0.f,0.f,0.f};

    auto stage = [&](int buf, int kb){
        #pragma unroll
        for (int u=0;u<4;++u){
            int idx = u*256 + tid;
            int row = idx>>3, g = (idx&7) ^ (row&7);
            gl_lds16(Ap + (long)row*lda + kb + g*8, &As[buf][(u*256+wvu)*8]);
        }
        #pragma unroll
        for (int u=0;u<BN/32;++u){
            int idx = u*256 + tid;
            int row = idx>>3, g = (idx&7) ^ (row&7);
            gl_lds16(Bp + (long)row*ldb + kb + g*8, &Bs[buf][(u*256+wvu)*8]);
        }
    };

    const int kbeg = kc*Ksub;
    const int nk = Ksub >> 6;
    stage(0, kbeg);
    int cur = 0;
    for (int t=0; t<nk; ++t){
        if (t+1 < nk){
            stage(cur^1, kbeg + (t+1)*64);
            if constexpr (BN==64) asm volatile("s_waitcnt vmcnt(6)" ::: "memory");
            else                  asm volatile("s_waitcnt vmcnt(8)" ::: "memory");
        } else {
            asm volatile("s_waitcnt vmcnt(0)" ::: "memory");
        }
        __builtin_amdgcn_s_barrier();
        FENCE();
        #pragma unroll
        for (int ks=0; ks<64; ks+=32){
            bf16x8 af[4], bfr[NF];
            #pragma unroll
            for (int i=0;i<4;++i){
                int row = wr*64 + i*16 + (l&15);
                af[i] = *(const bf16x8*)&As[cur][row*64 + ((((ks>>3)+(l>>4)) ^ (row&7))<<3)];
            }
            #pragma unroll
            for (int j=0;j<NF;++j){
                int row = wc*(BN/2) + j*16 + (l&15);
                bfr[j] = *(const bf16x8*)&Bs[cur][row*64 + ((((ks>>3)+(l>>4)) ^ (row&7))<<3)];
            }
            #pragma unroll
            for (int i=0;i<4;++i)
                #pragma unroll
                for (int j=0;j<NF;++j)
                    acc[i][j] = __builtin_amdgcn_mfma_f32_16x16x32_bf16(af[i], bfr[j], acc[i][j], 0,0,0);
        }
        FENCE();
        __builtin_amdgcn_s_barrier();
        FENCE();
        cur ^= 1;
    }

    const int mb = blockIdx.x*128 + wr*64, nb = blockIdx.y*BN + wc*(BN/2);
    #pragma unroll
    for (int i=0;i<4;++i)
        #pragma unroll
        for (int j=0;j<NF;++j){
            int gm0 = mb + i*16 + ((l>>4)<<2);
            int gn  = nb + j*16 + (l&15);
            #pragma unroll
            for (int r=0;r<4;++r){
                int gm = gm0 + r;
                float vacc = acc[i][j][r];
                if (EPI==0){
                    ob[jz*bsC + (long)gm*ldc + gn] = __float2bfloat16(vacc);
                } else {
                    float g = sigmoidf_(vacc + bias0[gm]);
                    float mv = __bfloat162float(aux[jz*bsAux + (long)gn*auxld + gm]);
                    o0[jz*bsC + (long)gm*ldc + gn] = g*mv;
                }
            }
        }
}

// =======================================================================
// Implicit-GEMM 3x3 conv, counted-vmcnt dbuf pipeline.
// =======================================================================
__global__ __launch_bounds__(256) void cgemm2_k(
    const bf16* __restrict__ inpad, const bf16* __restrict__ W,
    float* __restrict__ part, int N)
{
    __shared__ bf16 As[2][128*64];
    __shared__ bf16 Bs[2][64*64];
    const int tid = threadIdx.x, l = tid & 63, wvu = tid & ~63;
    const int wr = tid>>7, wc = (tid>>6)&1;
    const int bx = blockIdx.x, by = blockIdx.y, kc = blockIdx.z;
    const int img = bx/18, m0 = (bx - img*18)*128;
    const bf16* Ab = inpad + (long)img*PADR*512;
    const bf16* Bb = W + (long)by*64*KC;
    f32x4 acc[4][2];
    #pragma unroll
    for (int i=0;i<4;++i){ acc[i][0]=(f32x4){0,0,0,0}; acc[i][1]=(f32x4){0,0,0,0}; }

    auto stageA = [&](int buf, int k0){
        int tap = k0 >> 9, ci0 = k0 & 511;
        int dy = tap/3, dx = tap - 3*dy;
        int shift = (dy-1)*50 + (dx-1);
        #pragma unroll
        for (int u=0;u<4;++u){
            int idx = u*256 + tid;
            int row = idx>>3;
            int om = m0 + row;
            int prow = om + 2*(om/48) + 51 + shift;
            int g = (idx&7) ^ (row&7);
            gl_lds16(Ab + (long)prow*512 + ci0 + g*8, &As[buf][(u*256+wvu)*8]);
        }
    };
    auto stageB = [&](int buf, int k0){
        #pragma unroll
        for (int u=0;u<2;++u){
            int idx = u*256 + tid;
            int row = idx>>3;
            int g = (idx&7) ^ (row&7);
            gl_lds16(Bb + (long)row*KC + k0 + g*8, &Bs[buf][(u*256+wvu)*8]);
        }
    };

    const int kbeg = kc*2304;
    stageA(0, kbeg); stageB(0, kbeg);
    int cur = 0;
    for (int t=0; t<36; ++t){
        if (t+1 < 36){
            stageA(cur^1, kbeg+(t+1)*64); stageB(cur^1, kbeg+(t+1)*64);
            asm volatile("s_waitcnt vmcnt(6)" ::: "memory");
        } else {
            asm volatile("s_waitcnt vmcnt(0)" ::: "memory");
        }
        __builtin_amdgcn_s_barrier();
        FENCE();
        #pragma unroll
        for (int ks=0; ks<64; ks+=32){
            bf16x8 af[4], bfr[2];
            #pragma unroll
            for (int i=0;i<4;++i){
                int row = wr*64 + i*16 + (l&15);
                af[i] = *(const bf16x8*)&As[cur][row*64 + ((((ks>>3)+(l>>4)) ^ (row&7))<<3)];
            }
            #pragma unroll
            for (int j=0;j<2;++j){
                int row = wc*32 + j*16 + (l&15);
                bfr[j] = *(const bf16x8*)&Bs[cur][row*64 + ((((ks>>3)+(l>>4)) ^ (row&7))<<3)];
            }
            #pragma unroll
            for (int i=0;i<4;++i)
                #pragma unroll
                for (int j=0;j<2;++j)
                    acc[i][j] = __builtin_amdgcn_mfma_f32_16x16x32_bf16(af[i], bfr[j], acc[i][j], 0,0,0);
        }
        FENCE();
        __builtin_amdgcn_s_barrier();
        FENCE();
        cur ^= 1;
    }

    float* pbase = part + (long)kc*N*6912 + (long)img*2304;
    #pragma unroll
    for (int i=0;i<4;++i)
        #pragma unroll
        for (int j=0;j<2;++j){
            int gm0 = m0 + wr*64 + i*16 + ((l>>4)<<2);
            int gn  = by*64 + wc*32 + j*16 + (l&15);
            *(f32x4*)&pbase[(long)gn*6912 + gm0] = acc[i][j];
        }
}

// ---- split-K reduce + bias + activation; DUAL r-branch fuses *h (rh) ----
template<int ACT, int DUAL>
__global__ __launch_bounds__(256) void cred_k(const float* __restrict__ part,
        const float* __restrict__ b0, const float* __restrict__ b1,
        float* __restrict__ o0, float* __restrict__ o1,
        const float* __restrict__ hmul, int N)
{
    int id = blockIdx.x*256 + threadIdx.x;
    int c = id / 6912, g = id - c*6912;
    int img = g / 2304, p = g - img*2304;
    float v = part[id] + part[id + (long)N*6912];
    if (DUAL && c >= 256){
        int co = c - 256;
        long oidx = (long)img*CP + (long)co*PIX + p;
        o1[oidx] = sigmoidf_(v + b1[co]) * hmul[oidx];
    } else {
        float r = v + b0[c];
        if (ACT==1) r = sigmoidf_(r);
        else if (ACT==2) r = tanhf(r);
        else r = fmaxf(r, 0.f);
        o0[(long)img*CP + (long)c*PIX + p] = r;
    }
}

__global__ __launch_bounds__(256) void padtr_k(const float* __restrict__ src,
        bf16* __restrict__ dst, int cofs)
{
    __shared__ float tile[64][65];
    const int img = blockIdx.z, p0 = blockIdx.x*64, c0 = blockIdx.y*64;
    const int t = threadIdx.x, tx = t&63, tq = t>>6;
    const float* s = src + (long)img*CP;
    #pragma unroll
    for (int u=0;u<16;++u){
        int r = tq + u*4;
        tile[r][tx] = s[(long)(c0+r)*PIX + p0 + tx];
    }
    __syncthreads();
    bf16* d = dst + (long)img*PADR*512 + cofs + c0;
    #pragma unroll
    for (int u=0;u<16;++u){
        int pl = tq + u*4;
        int p = p0 + pl;
        int prow = p + 2*(p/48) + 51;
        d[(long)prow*512 + tx] = __float2bfloat16(tile[tx][pl]);
    }
}

__global__ __launch_bounds__(256) void convw_k(const float* __restrict__ src,
        bf16* __restrict__ dst, int total)
{
    int idx = blockIdx.x*256 + threadIdx.x;
    if (idx >= total) return;
    int co = idx / KC, r = idx - co*KC;
    int tap = r >> 9, ci = r & 511;
    dst[idx] = __float2bfloat16(src[(long)co*KC + ci*9 + tap]);
}

__global__ __launch_bounds__(256) void prep_h_k(const float* __restrict__ h,
        bf16* __restrict__ hcp, bf16* __restrict__ hp)
{
    __shared__ float tile[64][65];
    const int i = blockIdx.z, p0 = blockIdx.x*64, c0 = blockIdx.y*64;
    const int t = threadIdx.x, tx = t&63, tq = t>>6;
    const float* src = h + (long)i*CP;
    #pragma unroll
    for (int s=0;s<16;++s){
        int r = tq + s*4;
        float v = src[(long)(c0+r)*PIX + p0 + tx];
        tile[r][tx] = v;
        hcp[(long)i*CP + (long)(c0+r)*PIX + p0 + tx] = __float2bfloat16(v);
    }
    __syncthreads();
    #pragma unroll
    for (int s=0;s<16;++s){
        int r = tq + s*4;
        hp[(long)i*CP + (long)(p0+r)*256 + c0 + tx] = __float2bfloat16(tile[tx][r]);
    }
}

__global__ __launch_bounds__(256) void convert_w_k(const float* __restrict__ wint,
    const float* __restrict__ wintra, const float* __restrict__ gw, bf16* __restrict__ o)
{
    int t = blockIdx.x*256 + threadIdx.x;
    int d = t >> 8, c = t & 255;
    o[t]          = __float2bfloat16(wint[c*256 + d]);
    o[65536 + t]  = __float2bfloat16(wintra[c*256 + d]);
    o[131072 + t] = __float2bfloat16(gw[t]);
}

__global__ __launch_bounds__(256) void gatesum_k(const float* __restrict__ g, float* __restrict__ out)
{
    int x = blockIdx.x*256 + threadIdx.x;
    int i = blockIdx.y;
    const float* gi = g + (long)i*3*CP;
    float4 a = ((const float4*)gi)[x];
    float4 b = ((const float4*)gi)[x + CP/4];
    float4 c = ((const float4*)gi)[x + CP/2];
    float4 r; r.x=a.x+b.x+c.x; r.y=a.y+b.y+c.y; r.z=a.z+b.z+c.z; r.w=a.w+b.w+c.w;
    ((float4*)(out + (long)i*CP))[x] = r;
}

__global__ __launch_bounds__(256) void backbone_k(
    const float* __restrict__ frames, const float* __restrict__ W,
    const float* __restrict__ bias, float* __restrict__ v, float* __restrict__ h)
{
    __shared__ float wl[3*64*4];
    const int n = blockIdx.z, o0 = blockIdx.y * 4;
    const int p = blockIdx.x * 256 + threadIdx.x;
    const int y = p / 48, x = p % 48;
    for (int e = threadIdx.x; e < 768; e += 256) {
        int o_sel = e / 192, rem = e % 192, ci = rem / 64, k = rem % 64;
        wl[(ci*64 + k)*4 + o_sel] = W[((long)(o0 + o_sel)*3 + ci)*64 + k];
    }
    __syncthreads();
    float acc[4] = {0.f,0.f,0.f,0.f};
    for (int ci = 0; ci < 3; ++ci) {
        const float* src = frames + (((long)n*3 + ci)*384) * 384;
        #pragma unroll
        for (int k = 0; k < 64; ++k) {
            int ky = k >> 3, kx = k & 7;
            float iv = src[(8*y + ky)*384 + 8*x + kx];
            float4 w = ((const float4*)wl)[ci*64 + k];
            acc[0] += iv*w.x; acc[1] += iv*w.y; acc[2] += iv*w.z; acc[3] += iv*w.w;
        }
    }
    #pragma unroll
    for (int oo = 0; oo < 4; ++oo) {
        float r = fmaxf(acc[oo] + bias[o0 + oo], 0.f);
        long idx = ((long)n*CCH + o0 + oo)*PIX + p;
        v[idx] = r; h[idx] = r;
    }
}

__global__ __launch_bounds__(256) void hupd_k(const float* __restrict__ zg, const float* __restrict__ hc,
                                              float* __restrict__ h)
{
    int idx = blockIdx.x*256 + threadIdx.x;
    float z = zg[idx];
    h[idx] = (1.f - z)*h[idx] + z*hc[idx];
}

__global__ __launch_bounds__(256) void maskpart_k(const float* __restrict__ yin,
        const float* __restrict__ W, float* __restrict__ part)
{
    __shared__ float wl[288];
    const int cb = blockIdx.y * 32;
    for (int e = threadIdx.x; e < 288; e += 256) wl[e] = W[cb*9 + e];
    __syncthreads();
    int id = blockIdx.x*256 + threadIdx.x;
    int n = id / PIX, p = id - n*PIX;
    int y = p / 48, x = p % 48;
    float acc = 0.f;
    for (int ci = 0; ci < 32; ++ci) {
        const float* src = yin + ((long)n*CCH + cb + ci)*PIX;
        #pragma unroll
        for (int dy = 0; dy < 3; ++dy) {
            int yy = y + dy - 1;
            #pragma unroll
            for (int dx = 0; dx < 3; ++dx) {
                int xx = x + dx - 1;
                float iv = (yy >= 0 && yy < 48 && xx >= 0 && xx < 48) ? src[yy*48 + xx] : 0.f;
                acc += iv * wl[ci*9 + dy*3 + dx];
            }
        }
    }
    part[(long)blockIdx.y*(3*PIX) + id] = acc;
}

__global__ __launch_bounds__(256) void maskred_k(const float* __restrict__ part,
        const float* __restrict__ bias, float* __restrict__ out)
{
    int id = blockIdx.x*256 + threadIdx.x;
    float acc = bias[0];
    #pragma unroll
    for (int s = 0; s < 8; ++s) acc += part[(long)s*(3*PIX) + id];
    out[id] = acc;
}

extern "C" void kernel_launch(void* const* d_in, const int* in_sizes, int n_in,
                              void* d_out, int out_size, void* d_ws, size_t ws_size,
                              hipStream_t stream)
{
    const float* frames     = (const float*)d_in[0];
    const float* backbone_w = (const float*)d_in[1];
    const float* backbone_b = (const float*)d_in[2];
    const float* W_intra    = (const float*)d_in[3];
    const float* W_inter    = (const float*)d_in[4];
    const float* gate_w     = (const float*)d_in[5];
    const float* gate_b     = (const float*)d_in[6];
    const float* Wz         = (const float*)d_in[7];
    const float* bz         = (const float*)d_in[8];
    const float* Wr         = (const float*)d_in[9];
    const float* br         = (const float*)d_in[10];
    const float* Wh         = (const float*)d_in[11];
    const float* bh         = (const float*)d_in[12];
    const float* ro_w1      = (const float*)d_in[13];
    const float* ro_b1      = (const float*)d_in[14];
    const float* ro_w2      = (const float*)d_in[15];
    const float* ro_b2      = (const float*)d_in[16];
    float* out = (float*)d_out;
    float* ws  = (float*)d_ws;

    float* h    = ws + 0L*NCP;
    float* v    = ws + 1L*NCP;
    float* magg = ws + 2L*NCP;
    float* zg   = ws + 3L*NCP;   // conv: z-gate | attn: gated[9] (zg..rhg = 3 NCP)
    float* rg   = ws + 4L*NCP;
    float* rhg  = ws + 5L*NCP;
    float* hcmb = ws + 6L*NCP;   // hc (GRU)
    float* S    = ws + 7L*NCP;

    float* Mb9f   = S;                        // attn: 9*CP bf16 | conv: partials
    float* hp16f  = S + 7962624;
    float* hcp16f = hp16f + 884736;
    float* t16f   = hcp16f + 884736;
    float* ti16f  = t16f + 884736;
    float* wbase  = S + 11501568;
    bf16* Wint_t   = (bf16*)wbase;
    bf16* Wintra_t = Wint_t + 65536;
    bf16* gatew16  = Wint_t + 131072;
    bf16* cw16     = (bf16*)(wbase + 98304);  // 1024 x 4608 bf16
    bf16* inpad    = (bf16*)(wbase + 98304 + 2359296);
    float* maskp   = wbase + 98304 + 2359296 + 1929216;

    bf16* Mb9    = (bf16*)Mb9f;
    bf16* hp16   = (bf16*)hp16f;
    bf16* hcp16  = (bf16*)hcp16f;
    bf16* t16    = (bf16*)t16f;
    bf16* ti16   = (bf16*)ti16f;
    float* hc    = hcmb;
    float* gated = zg;                        // 9*CP fp32 = zg+rg+rhg
    float* cpart = Mb9f;

    dim3 b256(256);

    hipMemsetAsync(inpad, 0, 3858432*sizeof(bf16), stream);
    backbone_k<<<dim3(9,64,3), b256, 0, stream>>>(frames, backbone_w, backbone_b, v, h);
    convert_w_k<<<dim3(256), b256, 0, stream>>>(W_inter, W_intra, gate_w, Wint_t);
    convw_k<<<dim3(4608), b256, 0, stream>>>(Wz, cw16, 256*KC);
    convw_k<<<dim3(4608), b256, 0, stream>>>(Wr, cw16 + 256L*KC, 256*KC);
    convw_k<<<dim3(4608), b256, 0, stream>>>(Wh, cw16 + 512L*KC, 256*KC);
    convw_k<<<dim3(4608), b256, 0, stream>>>(ro_w1, cw16 + 768L*KC, 256*KC);

    for (int it = 0; it < 3; ++it) {
        // ---- attention phase ----
        prep_h_k<<<dim3(36,4,3), b256, 0, stream>>>(h, hcp16, hp16);
        mgemm_k<0,64><<<dim3(54,4,2), b256, 0, stream>>>(hp16, hp16, -1, Wint_t,
            nullptr, t16, nullptr, nullptr,
            6912,256, 256,256,256, 0, 0L,65536L,1769472L,0L, 2, 256, 0L);
        fattn_k<<<dim3(18,1,9), dim3(512), 0, stream>>>(t16, ti16, hp16, hcp16, Mb9);
        mgemm_k<2,64><<<dim3(2,36,9), b256, 0, stream>>>(gatew16, gatew16, -1,
            Mb9, gated, nullptr, Mb9, gate_b,
            256,2304, 256,256,PIX, 256, 0L,(long)CP,(long)CP,(long)CP,
            9, 256, 0L);
        gatesum_k<<<dim3(576,3), b256, 0, stream>>>(gated, magg);
        // ---- conv phase (implicit GEMM) ----
        padtr_k<<<dim3(36,4,3), b256, 0, stream>>>(magg, inpad, 0);
        padtr_k<<<dim3(36,4,3), b256, 0, stream>>>(h,    inpad, 256);
        cgemm2_k<<<dim3(54,8,2), b256, 0, stream>>>(inpad, cw16, cpart, 512);
        cred_k<1,1><<<dim3(13824), b256, 0, stream>>>(cpart, bz, br, zg, rhg, h, 512);
        padtr_k<<<dim3(36,4,3), b256, 0, stream>>>(rhg, inpad, 256);
        cgemm2_k<<<dim3(54,4,2), b256, 0, stream>>>(inpad, cw16 + 512L*KC, cpart, 256);
        cred_k<2,0><<<dim3(6912), b256, 0, stream>>>(cpart, bh, nullptr, hc, nullptr, nullptr, 256);
        hupd_k<<<dim3(6912), b256, 0, stream>>>(zg, hc, h);
    }

    // ---- readout ----
    padtr_k<<<dim3(36,4,3), b256, 0, stream>>>(h, inpad, 0);
    padtr_k<<<dim3(36,4,3), b256, 0, stream>>>(v, inpad, 256);
    cgemm2_k<<<dim3(54,4,2), b256, 0, stream>>>(inpad, cw16 + 768L*KC, cpart, 256);
    cred_k<3,0><<<dim3(6912), b256, 0, stream>>>(cpart, ro_b1, nullptr, zg, nullptr, nullptr, 256);
    maskpart_k<<<dim3(27,8), b256, 0, stream>>>(zg, ro_w2, maskp);
    maskred_k<<<dim3(27), b256, 0, stream>>>(maskp, ro_b2, out);
}